// Round 9
// baseline (708.464 us; speedup 1.0000x reference)
//
#include <hip/hip_runtime.h>
#include <hip/hip_bf16.h>
#include <math.h>

#define B_    256
#define S_    50
#define I_    1024
#define H_    512
#define G3_   1536   // 3*H
#define SENT_ 512
#define DOC_  1024

typedef short bf16x8 __attribute__((ext_vector_type(8)));
typedef float f32x4 __attribute__((ext_vector_type(4)));

__device__ __forceinline__ float sigf(float x) { return 1.0f / (1.0f + __expf(-x)); }
__device__ __forceinline__ float b2f(short s) {
  unsigned u = ((unsigned)(unsigned short)s) << 16;
  float f;
  __builtin_memcpy(&f, &u, 4);
  return f;
}

// async global->LDS, 16B per lane. LDS dest = wave-uniform base + lane*16.
__device__ __forceinline__ void gload16(const void* g, void* l) {
  __builtin_amdgcn_global_load_lds((const __attribute__((address_space(1))) void*)g,
                                   (__attribute__((address_space(3))) void*)l, 16, 0, 0);
}

// ===========================================================================
// bf16 MFMA GEMM (m97 structure), 128x128 tile, BK=64 — unchanged from R2.
// ===========================================================================
__global__ __launch_bounds__(256) void mfma_xg(
    const __hip_bfloat16* __restrict__ x,
    const __hip_bfloat16* __restrict__ Wf, const float* __restrict__ bf_,
    const __hip_bfloat16* __restrict__ Wb, const float* __restrict__ bb_,
    __hip_bfloat16* __restrict__ xgf, __hip_bfloat16* __restrict__ xgb) {
  __shared__ __align__(16) short As[128 * 64];
  __shared__ __align__(16) short Ws[128 * 64];
  const int dir = blockIdx.z;
  const __hip_bfloat16* W = dir ? Wb : Wf;
  const float* bias = dir ? bb_ : bf_;
  __hip_bfloat16* out = dir ? xgb : xgf;
  const int tid = threadIdx.x;
  const int m0 = blockIdx.y * 128, n0 = blockIdx.x * 128;
  const int s = blockIdx.y >> 1, b_base = (blockIdx.y & 1) * 128;
  const int s_eff = dir ? (S_ - 1 - s) : s;
  const int lane = tid & 63, w = tid >> 6;
  const int moff = (w & 1) * 64, noff = (w >> 1) * 64;
  const int frow = lane & 15, quad = lane >> 4;
  const int rr = tid >> 3, gs = tid & 7;
  f32x4 acc[4][4] = {};
  for (int kc = 0; kc < I_; kc += 64) {
#pragma unroll
    for (int iss = 0; iss < 4; iss++) {
      int r = iss * 32 + rr;
      int col = kc + ((gs ^ (r & 7)) << 3);
      gload16(x + ((size_t)(b_base + r) * S_ + s_eff) * I_ + col, &As[(iss * 256 + w * 64) * 8]);
    }
#pragma unroll
    for (int iss = 0; iss < 4; iss++) {
      int r = iss * 32 + rr;
      int col = kc + ((gs ^ (r & 7)) << 3);
      gload16(W + (size_t)(n0 + r) * I_ + col, &Ws[(iss * 256 + w * 64) * 8]);
    }
    __syncthreads();
#pragma unroll
    for (int ks = 0; ks < 2; ks++) {
      int kg = ks * 4 + quad;
      bf16x8 af[4], bfr[4];
#pragma unroll
      for (int mf = 0; mf < 4; mf++) {
        int r = moff + mf * 16 + frow;
        af[mf] = *(const bf16x8*)&As[(r * 8 + (kg ^ (r & 7))) * 8];
      }
#pragma unroll
      for (int nf = 0; nf < 4; nf++) {
        int r = noff + nf * 16 + frow;
        bfr[nf] = *(const bf16x8*)&Ws[(r * 8 + (kg ^ (r & 7))) * 8];
      }
#pragma unroll
      for (int mf = 0; mf < 4; mf++)
#pragma unroll
        for (int nf = 0; nf < 4; nf++)
          acc[mf][nf] = __builtin_amdgcn_mfma_f32_16x16x32_bf16(af[mf], bfr[nf], acc[mf][nf], 0, 0, 0);
    }
    __syncthreads();
  }
#pragma unroll
  for (int mf = 0; mf < 4; mf++) {
    int rowb = m0 + moff + mf * 16 + quad * 4;
#pragma unroll
    for (int nf = 0; nf < 4; nf++) {
      int col = n0 + noff + nf * 16 + frow;
      float bv = bias[col];
      f32x4 c = acc[mf][nf];
#pragma unroll
      for (int rg = 0; rg < 4; rg++)
        out[(size_t)(rowb + rg) * G3_ + col] = __float2bfloat16(c[rg] + bv);
    }
  }
}

template <int ACT, bool HASBIAS>
__global__ __launch_bounds__(256) void mfma_nt(
    const __hip_bfloat16* __restrict__ A, const __hip_bfloat16* __restrict__ W,
    const float* __restrict__ bias, __hip_bfloat16* __restrict__ outb, int N, int K) {
  __shared__ __align__(16) short As[128 * 64];
  __shared__ __align__(16) short Ws[128 * 64];
  const int tid = threadIdx.x;
  const int m0 = blockIdx.y * 128, n0 = blockIdx.x * 128;
  const int lane = tid & 63, w = tid >> 6;
  const int moff = (w & 1) * 64, noff = (w >> 1) * 64;
  const int frow = lane & 15, quad = lane >> 4;
  const int rr = tid >> 3, gs = tid & 7;
  f32x4 acc[4][4] = {};
  for (int kc = 0; kc < K; kc += 64) {
#pragma unroll
    for (int iss = 0; iss < 4; iss++) {
      int r = iss * 32 + rr;
      int col = kc + ((gs ^ (r & 7)) << 3);
      gload16(A + (size_t)(m0 + r) * K + col, &As[(iss * 256 + w * 64) * 8]);
    }
#pragma unroll
    for (int iss = 0; iss < 4; iss++) {
      int r = iss * 32 + rr;
      int col = kc + ((gs ^ (r & 7)) << 3);
      gload16(W + (size_t)(n0 + r) * K + col, &Ws[(iss * 256 + w * 64) * 8]);
    }
    __syncthreads();
#pragma unroll
    for (int ks = 0; ks < 2; ks++) {
      int kg = ks * 4 + quad;
      bf16x8 af[4], bfr[4];
#pragma unroll
      for (int mf = 0; mf < 4; mf++) {
        int r = moff + mf * 16 + frow;
        af[mf] = *(const bf16x8*)&As[(r * 8 + (kg ^ (r & 7))) * 8];
      }
#pragma unroll
      for (int nf = 0; nf < 4; nf++) {
        int r = noff + nf * 16 + frow;
        bfr[nf] = *(const bf16x8*)&Ws[(r * 8 + (kg ^ (r & 7))) * 8];
      }
#pragma unroll
      for (int mf = 0; mf < 4; mf++)
#pragma unroll
        for (int nf = 0; nf < 4; nf++)
          acc[mf][nf] = __builtin_amdgcn_mfma_f32_16x16x32_bf16(af[mf], bfr[nf], acc[mf][nf], 0, 0, 0);
    }
    __syncthreads();
  }
#pragma unroll
  for (int mf = 0; mf < 4; mf++) {
    int rowb = m0 + moff + mf * 16 + quad * 4;
#pragma unroll
    for (int nf = 0; nf < 4; nf++) {
      int col = n0 + noff + nf * 16 + frow;
      float bv = HASBIAS ? bias[col] : 0.f;
      f32x4 c = acc[mf][nf];
#pragma unroll
      for (int rg = 0; rg < 4; rg++) {
        float v = c[rg] + bv;
        if (ACT == 1) v = fmaxf(v, 0.f);
        outb[(size_t)(rowb + rg) * N + col] = __float2bfloat16(v);
      }
    }
  }
}

// ---------------------------------------------------------------------------
// Persistent GRU scan v4 = R8 v3 + xg(t+1) register prefetch before the
// barrier poll (overlaps L2 latency with the wait).
// ---------------------------------------------------------------------------
__global__ __launch_bounds__(256, 1) void gru_persistent(
    const __hip_bfloat16* __restrict__ xgf, const __hip_bfloat16* __restrict__ xgb,
    const __hip_bfloat16* __restrict__ Wpf, const __hip_bfloat16* __restrict__ Wpb,
    const float* __restrict__ bhhf, const float* __restrict__ bhhb,
    __hip_bfloat16* __restrict__ h16a, __hip_bfloat16* __restrict__ h16b,
    __hip_bfloat16* __restrict__ rnn,
    unsigned int* __restrict__ arrive) {
  __shared__ __align__(16) short Hs[32 * 512];  // 32 KB, XOR-swizzled
  const int bid = blockIdx.x;
  const int dir = bid >> 7;
  const int bt = (bid >> 4) & 7;
  const int jt = bid & 15;
  const int gi = bid >> 4;
  const int tid = threadIdx.x;
  const int w = tid >> 6, lane = tid & 63;
  const int frow = lane & 15, quad = lane >> 4;
  const int wm = w & 1, wn = w >> 1;
  const __hip_bfloat16* xg = dir ? xgb : xgf;
  const __hip_bfloat16* Wp = dir ? Wpb : Wpf;
  const float* bhh = dir ? bhhb : bhhf;

  unsigned int* my_flag = arrive + (size_t)bid * 64;

  const int j = jt * 32 + wn * 16 + frow;
  const int brow0 = bt * 32 + wm * 16 + quad * 4;
  const int ar = wm * 16 + frow;
  const float br = bhh[j], bz = bhh[H_ + j], bn = bhh[2 * H_ + j];

  bf16x8 wf[3][16];
#pragma unroll
  for (int g = 0; g < 3; g++)
#pragma unroll
    for (int ks = 0; ks < 16; ks++)
      wf[g][ks] = *(const bf16x8*)(Wp + (size_t)((jt * 2 + wn) * 48 + g * 16 + frow) * H_ +
                                   ks * 32 + quad * 8);

  float hreg[4] = {0.f, 0.f, 0.f, 0.f};
  union U16 { unsigned long long q[2]; bf16x8 v; };

  // prefetch xg(0)
  float xgv[4][3];
#pragma unroll
  for (int rg = 0; rg < 4; rg++) {
    const __hip_bfloat16* xr = xg + ((size_t)(brow0 + rg)) * G3_;
    xgv[rg][0] = __bfloat162float(xr[j]);
    xgv[rg][1] = __bfloat162float(xr[H_ + j]);
    xgv[rg][2] = __bfloat162float(xr[2 * H_ + j]);
  }

  for (int t = 0; t < S_; t++) {
    const __hip_bfloat16* hp = (t & 1) ? h16b : h16a;
    __hip_bfloat16* hn = (t & 1) ? h16a : h16b;
    // cooperative coherent stage of h(t) tile (32 rows x 512) into swizzled LDS
    const __hip_bfloat16* hbase = hp + (size_t)(dir * B_ + bt * 32) * H_;
#pragma unroll
    for (int i = 0; i < 8; i++) {
      int c = i * 256 + tid;
      int r = c >> 6, kg = c & 63;
      const unsigned long long* p = (const unsigned long long*)(hbase + (size_t)r * H_ + kg * 8);
      U16 u;
      u.q[0] = __hip_atomic_load(p, __ATOMIC_RELAXED, __HIP_MEMORY_SCOPE_AGENT);
      u.q[1] = __hip_atomic_load(p + 1, __ATOMIC_RELAXED, __HIP_MEMORY_SCOPE_AGENT);
      int q = r * 64 + (kg & 56) + ((kg & 7) ^ (r & 7));
      *(bf16x8*)&Hs[q * 8] = u.v;
    }
    __syncthreads();
    bf16x8 af[16];
#pragma unroll
    for (int ks = 0; ks < 16; ks++) {
      int g2 = ks * 4 + quad;
      int q = ar * 64 + (g2 & 56) + ((g2 & 7) ^ (ar & 7));
      af[ks] = *(const bf16x8*)&Hs[q * 8];
    }
    f32x4 acc[3] = {};
#pragma unroll
    for (int ks = 0; ks < 16; ks++)
#pragma unroll
      for (int g = 0; g < 3; g++)
        acc[g] = __builtin_amdgcn_mfma_f32_16x16x32_bf16(af[ks], wf[g][ks], acc[g], 0, 0, 0);

    const int s_orig = dir ? (S_ - 1 - t) : t;
#pragma unroll
    for (int rg = 0; rg < 4; rg++) {
      int b = brow0 + rg;
      float r = sigf(xgv[rg][0] + acc[0][rg] + br);
      float z = sigf(xgv[rg][1] + acc[1][rg] + bz);
      float n = tanhf(xgv[rg][2] + r * (acc[2][rg] + bn));
      float h = (1.f - z) * n + z * hreg[rg];
      hreg[rg] = h;
      __hip_bfloat16 hb = __float2bfloat16(h);
      unsigned short us;
      __builtin_memcpy(&us, &hb, 2);
      __hip_atomic_store((unsigned short*)(hn + (size_t)(dir * B_ + b) * H_ + j), us,
                         __ATOMIC_RELAXED, __HIP_MEMORY_SCOPE_AGENT);
      rnn[((size_t)b * S_ + s_orig) * (2 * H_) + dir * H_ + j] = hb;
    }

    if (t + 1 < S_) {
      // prefetch xg(t+1) BEFORE the barrier — latency overlaps the poll
      float xgn[4][3];
#pragma unroll
      for (int rg = 0; rg < 4; rg++) {
        const __hip_bfloat16* xr = xg + ((size_t)(t + 1) * B_ + brow0 + rg) * G3_;
        xgn[rg][0] = __bfloat162float(xr[j]);
        xgn[rg][1] = __bfloat162float(xr[H_ + j]);
        xgn[rg][2] = __bfloat162float(xr[2 * H_ + j]);
      }
      __syncthreads();  // drains vmcnt (h stores at coherence point) + Hs reuse
      if (tid == 0)
        __hip_atomic_store(my_flag, (unsigned)(t + 1), __ATOMIC_RELAXED,
                           __HIP_MEMORY_SCOPE_AGENT);
      if (w == 0) {
        unsigned int* fl = arrive + (size_t)(gi * 16 + (lane & 15)) * 64;
        for (int spin = 0; spin < (1 << 17); spin++) {
          unsigned v = (lane < 16)
                           ? __hip_atomic_load(fl, __ATOMIC_RELAXED, __HIP_MEMORY_SCOPE_AGENT)
                           : (unsigned)(t + 1);
          if (__ballot(v >= (unsigned)(t + 1)) == ~0ull) break;
          __builtin_amdgcn_s_sleep(1);
        }
      }
      __syncthreads();
#pragma unroll
      for (int rg = 0; rg < 4; rg++) {
        xgv[rg][0] = xgn[rg][0]; xgv[rg][1] = xgn[rg][1]; xgv[rg][2] = xgn[rg][2];
      }
    }
  }
}

// ---------------------------------------------------------------------------
// fp32 tiled GEMM (small doc GEMMs)
// ---------------------------------------------------------------------------
template <int ACT>
__global__ __launch_bounds__(256) void gemm_nt(const float* __restrict__ A,
                                               const float* __restrict__ W,
                                               const float* __restrict__ bias,
                                               float* __restrict__ C, int N, int K) {
  __shared__ float As[16][68];
  __shared__ float Bs[16][68];
  const int t = threadIdx.x;
  const int tx = t & 15, ty = t >> 4;
  const int m0 = blockIdx.y * 64, n0 = blockIdx.x * 64;
  const int lr = t >> 2, lc = t & 3;
  const float* Arow = A + (size_t)(m0 + lr) * K;
  const float* Wrow = W + (size_t)(n0 + lr) * K;
  float acc[4][4] = {};
  for (int kc = 0; kc < K; kc += 16) {
    float4 av = *(const float4*)(Arow + kc + lc * 4);
    float4 wv = *(const float4*)(Wrow + kc + lc * 4);
    As[lc * 4 + 0][lr] = av.x; As[lc * 4 + 1][lr] = av.y;
    As[lc * 4 + 2][lr] = av.z; As[lc * 4 + 3][lr] = av.w;
    Bs[lc * 4 + 0][lr] = wv.x; Bs[lc * 4 + 1][lr] = wv.y;
    Bs[lc * 4 + 2][lr] = wv.z; Bs[lc * 4 + 3][lr] = wv.w;
    __syncthreads();
#pragma unroll
    for (int k = 0; k < 16; k++) {
      float4 a4 = *(const float4*)&As[k][ty * 4];
      float4 b4 = *(const float4*)&Bs[k][tx * 4];
      float ar[4] = {a4.x, a4.y, a4.z, a4.w};
      float br[4] = {b4.x, b4.y, b4.z, b4.w};
#pragma unroll
      for (int i = 0; i < 4; i++)
#pragma unroll
        for (int jx = 0; jx < 4; jx++) acc[i][jx] = fmaf(ar[i], br[jx], acc[i][jx]);
    }
    __syncthreads();
  }
  float4 bv = *(const float4*)&bias[n0 + tx * 4];
  float bb[4] = {bv.x, bv.y, bv.z, bv.w};
#pragma unroll
  for (int i = 0; i < 4; i++) {
    float o[4];
#pragma unroll
    for (int jx = 0; jx < 4; jx++) {
      float v = acc[i][jx] + bb[jx];
      if (ACT == 1) v = fmaxf(v, 0.f);
      if (ACT == 2) v = tanhf(v);
      o[jx] = v;
    }
    *(float4*)&C[(size_t)(m0 + ty * 4 + i) * N + n0 + tx * 4] = float4{o[0], o[1], o[2], o[3]};
  }
}

// ------------------------- fused prep kernel -------------------------------
// x cast + 3 weight casts + 2 W_hh packs + LDS-tiled Wsim transpose +
// h16a zero + arrive zero + posseg, segmented by blockIdx.x.
#define PREP_XC    12800                    // x cast (13,107,200 / 1024)
#define PREP_CAST1 (PREP_XC + 1536)         // Wihf
#define PREP_CAST2 (PREP_CAST1 + 1536)      // Wihb
#define PREP_CAST3 (PREP_CAST2 + 512)       // Wsent
#define PREP_PACK1 (PREP_CAST3 + 768)       // Whhf pack
#define PREP_PACK2 (PREP_PACK1 + 768)       // Whhb pack
#define PREP_TSIM  (PREP_PACK2 + 256)       // Wsim transpose, 32x32 tiles (16x16)
#define PREP_ZH    (PREP_TSIM + 128)        // h16a zero
#define PREP_ZF    (PREP_ZH + 16)           // arrive zero
#define PREP_POS   (PREP_ZF)                // posseg (single block)
__global__ __launch_bounds__(256) void prep_all(
    const float* __restrict__ x, const float* __restrict__ Wihf,
    const float* __restrict__ Wihb, const float* __restrict__ Wsent,
    const float* __restrict__ Whhf, const float* __restrict__ Whhb,
    const float* __restrict__ Wsim,
    const float* __restrict__ pos_emb, const float* __restrict__ pos_lin,
    const float* __restrict__ seg_emb, const float* __restrict__ seg_lin,
    __hip_bfloat16* __restrict__ x_bf,
    __hip_bfloat16* __restrict__ Wihf_b, __hip_bfloat16* __restrict__ Wihb_b,
    __hip_bfloat16* __restrict__ Wsent_b, __hip_bfloat16* __restrict__ Wpf,
    __hip_bfloat16* __restrict__ Wpb, __hip_bfloat16* __restrict__ WsimT_b,
    __hip_bfloat16* __restrict__ h16a, unsigned int* __restrict__ arrive,
    float* __restrict__ pos_logits, float* __restrict__ seg_vals) {
  const int blk = blockIdx.x, tid = threadIdx.x;
  if (blk < PREP_XC) {
    int i = blk * 1024 + tid * 4;
    float4 v = *(const float4*)(x + i);
    x_bf[i] = __float2bfloat16(v.x); x_bf[i + 1] = __float2bfloat16(v.y);
    x_bf[i + 2] = __float2bfloat16(v.z); x_bf[i + 3] = __float2bfloat16(v.w);
  } else if (blk < PREP_CAST2) {
    const float* src = (blk < PREP_CAST1) ? Wihf : Wihb;
    __hip_bfloat16* dst = (blk < PREP_CAST1) ? Wihf_b : Wihb_b;
    int lb = (blk < PREP_CAST1) ? blk - PREP_XC : blk - PREP_CAST1;
    int i = lb * 1024 + tid * 4;
    float4 v = *(const float4*)(src + i);
    dst[i] = __float2bfloat16(v.x); dst[i + 1] = __float2bfloat16(v.y);
    dst[i + 2] = __float2bfloat16(v.z); dst[i + 3] = __float2bfloat16(v.w);
  } else if (blk < PREP_CAST3) {
    int i = (blk - PREP_CAST2) * 1024 + tid * 4;
    float4 v = *(const float4*)(Wsent + i);
    Wsent_b[i] = __float2bfloat16(v.x); Wsent_b[i + 1] = __float2bfloat16(v.y);
    Wsent_b[i + 2] = __float2bfloat16(v.z); Wsent_b[i + 3] = __float2bfloat16(v.w);
  } else if (blk < PREP_PACK2) {  // W_hh packs: p = (j>>4)*48 + g*16 + (j&15)
    const float* src = (blk < PREP_PACK1) ? Whhf : Whhb;
    __hip_bfloat16* dst = (blk < PREP_PACK1) ? Wpf : Wpb;
    int lb = (blk < PREP_PACK1) ? blk - PREP_CAST3 : blk - PREP_PACK1;
    int e = lb * 1024 + tid * 4;
    int row = e >> 9, k = e & 511;  // row = g*512 + j
    int g = row >> 9, j = row & 511;
    int p = (j >> 4) * 48 + g * 16 + (j & 15);
    float4 v = *(const float4*)(src + (size_t)row * 512 + k);
    __hip_bfloat16* d = dst + (size_t)p * 512 + k;
    d[0] = __float2bfloat16(v.x); d[1] = __float2bfloat16(v.y);
    d[2] = __float2bfloat16(v.z); d[3] = __float2bfloat16(v.w);
  } else if (blk < PREP_TSIM) {  // 32x32 LDS tile transpose, coalesced both ways
    __shared__ float tile[32][33];
    int tb = blk - PREP_PACK2;
    int ti = tb >> 4, tj = tb & 15;  // 16x16 tiles of 32x32
    int r = tid >> 3, c4 = (tid & 7) * 4;
    float4 v = *(const float4*)(Wsim + (size_t)(ti * 32 + r) * 512 + tj * 32 + c4);
    tile[r][c4] = v.x; tile[r][c4 + 1] = v.y; tile[r][c4 + 2] = v.z; tile[r][c4 + 3] = v.w;
    __syncthreads();
    // write transposed: row = tj*32 + r, cols ti*32 + c4..c4+3
    __hip_bfloat16* d = WsimT_b + (size_t)(tj * 32 + r) * 512 + ti * 32 + c4;
    d[0] = __float2bfloat16(tile[c4][r]);
    d[1] = __float2bfloat16(tile[c4 + 1][r]);
    d[2] = __float2bfloat16(tile[c4 + 2][r]);
    d[3] = __float2bfloat16(tile[c4 + 3][r]);
  } else if (blk < PREP_ZH) {
    int i = (blk - PREP_TSIM) * 2048 + tid * 8;
    float4 z = {0.f, 0.f, 0.f, 0.f};
    *(float4*)((short*)h16a + i) = z;
  } else if (blk < PREP_ZF) {
    int i = (blk - PREP_ZH) * 1024 + tid * 4;
    float4 z = {0.f, 0.f, 0.f, 0.f};
    *(float4*)(arrive + i) = z;
  } else {  // posseg
    if (tid < S_) {
      int idx = tid + 1; if (idx > 25) idx = 25;
      float a = 0.f;
      for (int k = 0; k < 50; k++) a += pos_emb[idx * 50 + k] * pos_lin[k];
      pos_logits[tid] = a;
    }
    if (tid < 5) {
      float a = 0.f;
      for (int k = 0; k < 50; k++) a += seg_emb[tid * 50 + k] * seg_lin[k];
      seg_vals[tid] = a;
    }
  }
}

__global__ __launch_bounds__(256) void avg_kernel(const __hip_bfloat16* __restrict__ sent,
                                                  const int* __restrict__ ns,
                                                  float* __restrict__ avg) {
  int b = blockIdx.x, tid = threadIdx.x;
  const __hip_bfloat16* base = sent + (size_t)b * S_ * SENT_;
  float a0 = 0.f, a1 = 0.f;
  for (int s = 0; s < S_; s++) {
    a0 += __bfloat162float(base[s * SENT_ + tid]);
    a1 += __bfloat162float(base[s * SENT_ + 256 + tid]);
  }
  float inv = 1.0f / (float)ns[b];
  avg[(size_t)b * SENT_ + tid] = a0 * inv;
  avg[(size_t)b * SENT_ + 256 + tid] = a1 * inv;
}

// 4 waves per block, one (b,s) per wave
__global__ __launch_bounds__(256) void static_kernel(
    const __hip_bfloat16* __restrict__ sent, const float* __restrict__ doc,
    const float* __restrict__ wcont, const float* __restrict__ bcont,
    const int* __restrict__ ns, const float* __restrict__ pos_logits,
    const float* __restrict__ seg_vals, const float* __restrict__ bias,
    float* __restrict__ st) {
  int bs = blockIdx.x * 4 + (threadIdx.x >> 6);
  int b = bs / S_, s = bs % S_;
  int lane = threadIdx.x & 63;
  const __hip_bfloat16* sr = sent + (size_t)bs * SENT_;
  const float* dr = doc + (size_t)b * SENT_;
  float a0 = 0.f, a1 = 0.f;
#pragma unroll
  for (int ii = 0; ii < 8; ii++) {
    int k = ii * 64 + lane;
    float v = __bfloat162float(sr[k]);
    a0 += v * wcont[k];
    a1 += v * dr[k];
  }
#pragma unroll
  for (int off = 32; off; off >>= 1) {
    a0 += __shfl_down(a0, off);
    a1 += __shfl_down(a1, off);
  }
  if (lane == 0) {
    float chunk = rintf((float)ns[b] * 0.25f);
    float relf = ceilf((float)(s + 1) / chunk);
    relf = fminf(fmaxf(relf, 0.f), 4.f);
    int rel = (int)relf;
    st[s * B_ + b] = a0 + bcont[0] + a1 + pos_logits[s] + seg_vals[rel] + bias[0];
  }
}

// One 64-lane wave per batch element. Summary in 8 regs/lane; pure shfl
// reduction — zero LDS, zero __syncthreads (vs 100/block in R8).
__global__ __launch_bounds__(64) void novelty_wave(
    const __hip_bfloat16* __restrict__ sent, const __hip_bfloat16* __restrict__ U,
    const float* __restrict__ st, float* __restrict__ out) {
  int b = blockIdx.x, lane = threadIdx.x;
  float s[8] = {0.f, 0.f, 0.f, 0.f, 0.f, 0.f, 0.f, 0.f};
  for (int t = 0; t < S_; t++) {
    bf16x8 uv = *(const bf16x8*)(U + ((size_t)b * S_ + t) * SENT_ + lane * 8);
    float p = 0.f;
#pragma unroll
    for (int k = 0; k < 8; k++) p += b2f(uv[k]) * tanhf(s[k]);
#pragma unroll
    for (int off = 32; off; off >>= 1) p += __shfl_down(p, off);
    float sim = __shfl(p, 0);
    float logit = st[t * B_ + b] - sim;
    if (lane == 0) out[(size_t)t * B_ + b] = logit;
    float sg = sigf(logit);
    bf16x8 sv = *(const bf16x8*)(sent + ((size_t)b * S_ + t) * SENT_ + lane * 8);
#pragma unroll
    for (int k = 0; k < 8; k++) s[k] += b2f(sv[k]) * sg;
  }
}

extern "C" void kernel_launch(void* const* d_in, const int* in_sizes, int n_in,
                              void* d_out, int out_size, void* d_ws, size_t ws_size,
                              hipStream_t stream) {
  const float* x = (const float*)d_in[0];
  const int* ns = (const int*)d_in[1];
  const float* Wihf = (const float*)d_in[2];
  const float* Whhf = (const float*)d_in[3];
  const float* bihf = (const float*)d_in[4];
  const float* bhhf = (const float*)d_in[5];
  const float* Wihb = (const float*)d_in[6];
  const float* Whhb = (const float*)d_in[7];
  const float* bihb = (const float*)d_in[8];
  const float* bhhb = (const float*)d_in[9];
  const float* Wsent = (const float*)d_in[10];
  const float* bsent = (const float*)d_in[11];
  const float* wcont = (const float*)d_in[12];
  const float* bcont = (const float*)d_in[13];
  const float* Wd1 = (const float*)d_in[14];
  const float* bd1 = (const float*)d_in[15];
  const float* Wd2 = (const float*)d_in[16];
  const float* bd2 = (const float*)d_in[17];
  const float* Wsim = (const float*)d_in[18];
  const float* bias = (const float*)d_in[19];
  const float* pos_emb = (const float*)d_in[20];
  const float* pos_lin = (const float*)d_in[21];
  const float* seg_emb = (const float*)d_in[22];
  const float* seg_lin = (const float*)d_in[23];
  float* out = (float*)d_out;

  char* base = (char*)d_ws;
  size_t off = 0;
  auto alloc = [&](size_t bytes) { char* p = base + off; off += (bytes + 255) & ~255ull; return p; };
  __hip_bfloat16* xgf_b  = (__hip_bfloat16*)alloc((size_t)S_ * B_ * G3_ * 2);
  __hip_bfloat16* xgb_b  = (__hip_bfloat16*)alloc((size_t)S_ * B_ * G3_ * 2);
  char* region1          = alloc((size_t)B_ * S_ * I_ * 2);  // x_bf, later sent_b+U_b
  __hip_bfloat16* x_bf   = (__hip_bfloat16*)region1;
  __hip_bfloat16* sent_b = (__hip_bfloat16*)region1;
  __hip_bfloat16* U_b    = (__hip_bfloat16*)(region1 + (size_t)B_ * S_ * SENT_ * 2);
  __hip_bfloat16* rnn_b  = (__hip_bfloat16*)alloc((size_t)B_ * S_ * 2 * H_ * 2);
  __hip_bfloat16* Wihf_b = (__hip_bfloat16*)alloc((size_t)G3_ * I_ * 2);
  __hip_bfloat16* Wihb_b = (__hip_bfloat16*)alloc((size_t)G3_ * I_ * 2);
  __hip_bfloat16* Wpf    = (__hip_bfloat16*)alloc((size_t)G3_ * H_ * 2);
  __hip_bfloat16* Wpb    = (__hip_bfloat16*)alloc((size_t)G3_ * H_ * 2);
  __hip_bfloat16* Wsent_b= (__hip_bfloat16*)alloc((size_t)SENT_ * 2 * H_ * 2);
  __hip_bfloat16* WsimT_b= (__hip_bfloat16*)alloc((size_t)SENT_ * SENT_ * 2);
  __hip_bfloat16* h16a   = (__hip_bfloat16*)alloc(2 * (size_t)B_ * H_ * 2);
  __hip_bfloat16* h16b   = (__hip_bfloat16*)alloc(2 * (size_t)B_ * H_ * 2);
  unsigned int* arrive   = (unsigned int*)alloc(256 * 64 * 4);
  float* avg             = (float*)alloc((size_t)B_ * SENT_ * 4);
  float* d1buf           = (float*)alloc((size_t)B_ * DOC_ * 4);
  float* doc             = (float*)alloc((size_t)B_ * SENT_ * 4);
  float* st              = (float*)alloc((size_t)S_ * B_ * 4);
  float* poslog          = (float*)alloc(256);
  float* segvals         = (float*)alloc(64);
  (void)ws_size;

  // fully fused prep (x cast, weight casts/packs, tiled Wsim^T, zeros, posseg)
  prep_all<<<PREP_POS + 1, 256, 0, stream>>>(
      x, Wihf, Wihb, Wsent, Whhf, Whhb, Wsim, pos_emb, pos_lin, seg_emb, seg_lin,
      x_bf, Wihf_b, Wihb_b, Wsent_b, Wpf, Wpb, WsimT_b, h16a, arrive, poslog, segvals);

  mfma_xg<<<dim3(G3_ / 128, (S_ * B_) / 128, 2), 256, 0, stream>>>(x_bf, Wihf_b, bihf, Wihb_b, bihb, xgf_b, xgb_b);

  gru_persistent<<<dim3(256), dim3(256), 0, stream>>>(
      xgf_b, xgb_b, Wpf, Wpb, bhhf, bhhb, h16a, h16b, rnn_b, arrive);

  mfma_nt<1, true><<<dim3(SENT_ / 128, (B_ * S_) / 128), 256, 0, stream>>>(rnn_b, Wsent_b, bsent, sent_b, SENT_, 2 * H_);
  avg_kernel<<<B_, 256, 0, stream>>>(sent_b, ns, avg);
  gemm_nt<2><<<dim3(DOC_ / 64, B_ / 64), 256, 0, stream>>>(avg, Wd1, bd1, d1buf, DOC_, SENT_);
  gemm_nt<0><<<dim3(SENT_ / 64, B_ / 64), 256, 0, stream>>>(d1buf, Wd2, bd2, doc, SENT_, DOC_);
  static_kernel<<<(B_ * S_) / 4, 256, 0, stream>>>(sent_b, doc, wcont, bcont, ns, poslog, segvals, bias, st);

  mfma_nt<0, false><<<dim3(SENT_ / 128, (B_ * S_) / 128), 256, 0, stream>>>(sent_b, WsimT_b, nullptr, U_b, SENT_, SENT_);

  novelty_wave<<<B_, 64, 0, stream>>>(sent_b, U_b, st, out);
}

// Round 10
// 684.832 us; speedup vs baseline: 1.0345x; 1.0345x over previous
//
#include <hip/hip_runtime.h>
#include <hip/hip_bf16.h>
#include <math.h>

#define B_    256
#define S_    50
#define I_    1024
#define H_    512
#define G3_   1536   // 3*H
#define SENT_ 512
#define DOC_  1024

typedef short bf16x8 __attribute__((ext_vector_type(8)));
typedef float f32x4 __attribute__((ext_vector_type(4)));

__device__ __forceinline__ float sigf(float x) { return 1.0f / (1.0f + __expf(-x)); }
__device__ __forceinline__ float b2f(short s) {
  unsigned u = ((unsigned)(unsigned short)s) << 16;
  float f;
  __builtin_memcpy(&f, &u, 4);
  return f;
}

// async global->LDS, 16B per lane. LDS dest = wave-uniform base + lane*16.
__device__ __forceinline__ void gload16(const void* g, void* l) {
  __builtin_amdgcn_global_load_lds((const __attribute__((address_space(1))) void*)g,
                                   (__attribute__((address_space(3))) void*)l, 16, 0, 0);
}

// ===========================================================================
// bf16 MFMA GEMM (m97 structure), 128x128 tile, BK=64 — unchanged from R2.
// ===========================================================================
__global__ __launch_bounds__(256) void mfma_xg(
    const __hip_bfloat16* __restrict__ x,
    const __hip_bfloat16* __restrict__ Wf, const float* __restrict__ bf_,
    const __hip_bfloat16* __restrict__ Wb, const float* __restrict__ bb_,
    __hip_bfloat16* __restrict__ xgf, __hip_bfloat16* __restrict__ xgb) {
  __shared__ __align__(16) short As[128 * 64];
  __shared__ __align__(16) short Ws[128 * 64];
  const int dir = blockIdx.z;
  const __hip_bfloat16* W = dir ? Wb : Wf;
  const float* bias = dir ? bb_ : bf_;
  __hip_bfloat16* out = dir ? xgb : xgf;
  const int tid = threadIdx.x;
  const int m0 = blockIdx.y * 128, n0 = blockIdx.x * 128;
  const int s = blockIdx.y >> 1, b_base = (blockIdx.y & 1) * 128;
  const int s_eff = dir ? (S_ - 1 - s) : s;
  const int lane = tid & 63, w = tid >> 6;
  const int moff = (w & 1) * 64, noff = (w >> 1) * 64;
  const int frow = lane & 15, quad = lane >> 4;
  const int rr = tid >> 3, gs = tid & 7;
  f32x4 acc[4][4] = {};
  for (int kc = 0; kc < I_; kc += 64) {
#pragma unroll
    for (int iss = 0; iss < 4; iss++) {
      int r = iss * 32 + rr;
      int col = kc + ((gs ^ (r & 7)) << 3);
      gload16(x + ((size_t)(b_base + r) * S_ + s_eff) * I_ + col, &As[(iss * 256 + w * 64) * 8]);
    }
#pragma unroll
    for (int iss = 0; iss < 4; iss++) {
      int r = iss * 32 + rr;
      int col = kc + ((gs ^ (r & 7)) << 3);
      gload16(W + (size_t)(n0 + r) * I_ + col, &Ws[(iss * 256 + w * 64) * 8]);
    }
    __syncthreads();
#pragma unroll
    for (int ks = 0; ks < 2; ks++) {
      int kg = ks * 4 + quad;
      bf16x8 af[4], bfr[4];
#pragma unroll
      for (int mf = 0; mf < 4; mf++) {
        int r = moff + mf * 16 + frow;
        af[mf] = *(const bf16x8*)&As[(r * 8 + (kg ^ (r & 7))) * 8];
      }
#pragma unroll
      for (int nf = 0; nf < 4; nf++) {
        int r = noff + nf * 16 + frow;
        bfr[nf] = *(const bf16x8*)&Ws[(r * 8 + (kg ^ (r & 7))) * 8];
      }
#pragma unroll
      for (int mf = 0; mf < 4; mf++)
#pragma unroll
        for (int nf = 0; nf < 4; nf++)
          acc[mf][nf] = __builtin_amdgcn_mfma_f32_16x16x32_bf16(af[mf], bfr[nf], acc[mf][nf], 0, 0, 0);
    }
    __syncthreads();
  }
#pragma unroll
  for (int mf = 0; mf < 4; mf++) {
    int rowb = m0 + moff + mf * 16 + quad * 4;
#pragma unroll
    for (int nf = 0; nf < 4; nf++) {
      int col = n0 + noff + nf * 16 + frow;
      float bv = bias[col];
      f32x4 c = acc[mf][nf];
#pragma unroll
      for (int rg = 0; rg < 4; rg++)
        out[(size_t)(rowb + rg) * G3_ + col] = __float2bfloat16(c[rg] + bv);
    }
  }
}

template <int ACT, bool HASBIAS>
__global__ __launch_bounds__(256) void mfma_nt(
    const __hip_bfloat16* __restrict__ A, const __hip_bfloat16* __restrict__ W,
    const float* __restrict__ bias, __hip_bfloat16* __restrict__ outb, int N, int K) {
  __shared__ __align__(16) short As[128 * 64];
  __shared__ __align__(16) short Ws[128 * 64];
  const int tid = threadIdx.x;
  const int m0 = blockIdx.y * 128, n0 = blockIdx.x * 128;
  const int lane = tid & 63, w = tid >> 6;
  const int moff = (w & 1) * 64, noff = (w >> 1) * 64;
  const int frow = lane & 15, quad = lane >> 4;
  const int rr = tid >> 3, gs = tid & 7;
  f32x4 acc[4][4] = {};
  for (int kc = 0; kc < K; kc += 64) {
#pragma unroll
    for (int iss = 0; iss < 4; iss++) {
      int r = iss * 32 + rr;
      int col = kc + ((gs ^ (r & 7)) << 3);
      gload16(A + (size_t)(m0 + r) * K + col, &As[(iss * 256 + w * 64) * 8]);
    }
#pragma unroll
    for (int iss = 0; iss < 4; iss++) {
      int r = iss * 32 + rr;
      int col = kc + ((gs ^ (r & 7)) << 3);
      gload16(W + (size_t)(n0 + r) * K + col, &Ws[(iss * 256 + w * 64) * 8]);
    }
    __syncthreads();
#pragma unroll
    for (int ks = 0; ks < 2; ks++) {
      int kg = ks * 4 + quad;
      bf16x8 af[4], bfr[4];
#pragma unroll
      for (int mf = 0; mf < 4; mf++) {
        int r = moff + mf * 16 + frow;
        af[mf] = *(const bf16x8*)&As[(r * 8 + (kg ^ (r & 7))) * 8];
      }
#pragma unroll
      for (int nf = 0; nf < 4; nf++) {
        int r = noff + nf * 16 + frow;
        bfr[nf] = *(const bf16x8*)&Ws[(r * 8 + (kg ^ (r & 7))) * 8];
      }
#pragma unroll
      for (int mf = 0; mf < 4; mf++)
#pragma unroll
        for (int nf = 0; nf < 4; nf++)
          acc[mf][nf] = __builtin_amdgcn_mfma_f32_16x16x32_bf16(af[mf], bfr[nf], acc[mf][nf], 0, 0, 0);
    }
    __syncthreads();
  }
#pragma unroll
  for (int mf = 0; mf < 4; mf++) {
    int rowb = m0 + moff + mf * 16 + quad * 4;
#pragma unroll
    for (int nf = 0; nf < 4; nf++) {
      int col = n0 + noff + nf * 16 + frow;
      float bv = HASBIAS ? bias[col] : 0.f;
      f32x4 c = acc[mf][nf];
#pragma unroll
      for (int rg = 0; rg < 4; rg++) {
        float v = c[rg] + bv;
        if (ACT == 1) v = fmaxf(v, 0.f);
        outb[(size_t)(rowb + rg) * N + col] = __float2bfloat16(v);
      }
    }
  }
}

// ---------------------------------------------------------------------------
// Persistent GRU scan v5 = R9 v4 + wf REGISTER PINNING: asm "+v" makes the
// one-time W_hh loads opaque so the compiler cannot rematerialize them every
// step (R9: VGPR_Count=156 < 192 needed for wf => W reloaded from L2 each
// step, 192KB/block/step). With pin, expect VGPR_Count ~350.
// ---------------------------------------------------------------------------
__global__ __launch_bounds__(256, 1) void gru_persistent(
    const __hip_bfloat16* __restrict__ xgf, const __hip_bfloat16* __restrict__ xgb,
    const __hip_bfloat16* __restrict__ Wpf, const __hip_bfloat16* __restrict__ Wpb,
    const float* __restrict__ bhhf, const float* __restrict__ bhhb,
    __hip_bfloat16* __restrict__ h16a, __hip_bfloat16* __restrict__ h16b,
    __hip_bfloat16* __restrict__ rnn,
    unsigned int* __restrict__ arrive) {
  __shared__ __align__(16) short Hs[32 * 512];  // 32 KB, XOR-swizzled
  const int bid = blockIdx.x;
  const int dir = bid >> 7;
  const int bt = (bid >> 4) & 7;
  const int jt = bid & 15;
  const int gi = bid >> 4;
  const int tid = threadIdx.x;
  const int w = tid >> 6, lane = tid & 63;
  const int frow = lane & 15, quad = lane >> 4;
  const int wm = w & 1, wn = w >> 1;
  const __hip_bfloat16* xg = dir ? xgb : xgf;
  const __hip_bfloat16* Wp = dir ? Wpb : Wpf;
  const float* bhh = dir ? bhhb : bhhf;

  unsigned int* my_flag = arrive + (size_t)bid * 64;

  const int j = jt * 32 + wn * 16 + frow;
  const int brow0 = bt * 32 + wm * 16 + quad * 4;
  const int ar = wm * 16 + frow;
  const float br = bhh[j], bz = bhh[H_ + j], bn = bhh[2 * H_ + j];

  bf16x8 wf[3][16];
#pragma unroll
  for (int g = 0; g < 3; g++)
#pragma unroll
    for (int ks = 0; ks < 16; ks++)
      wf[g][ks] = *(const bf16x8*)(Wp + (size_t)((jt * 2 + wn) * 48 + g * 16 + frow) * H_ +
                                   ks * 32 + quad * 8);
  // pin: opaque redefinition — compiler cannot rematerialize the loads
#pragma unroll
  for (int g = 0; g < 3; g++)
#pragma unroll
    for (int ks = 0; ks < 16; ks++)
      asm volatile("" : "+v"(wf[g][ks]));

  float hreg[4] = {0.f, 0.f, 0.f, 0.f};
  union U16 { unsigned long long q[2]; bf16x8 v; };

  // prefetch xg(0)
  float xgv[4][3];
#pragma unroll
  for (int rg = 0; rg < 4; rg++) {
    const __hip_bfloat16* xr = xg + ((size_t)(brow0 + rg)) * G3_;
    xgv[rg][0] = __bfloat162float(xr[j]);
    xgv[rg][1] = __bfloat162float(xr[H_ + j]);
    xgv[rg][2] = __bfloat162float(xr[2 * H_ + j]);
  }

  for (int t = 0; t < S_; t++) {
    const __hip_bfloat16* hp = (t & 1) ? h16b : h16a;
    __hip_bfloat16* hn = (t & 1) ? h16a : h16b;
    const __hip_bfloat16* hbase = hp + (size_t)(dir * B_ + bt * 32) * H_;
#pragma unroll
    for (int i = 0; i < 8; i++) {
      int c = i * 256 + tid;
      int r = c >> 6, kg = c & 63;
      const unsigned long long* p = (const unsigned long long*)(hbase + (size_t)r * H_ + kg * 8);
      U16 u;
      u.q[0] = __hip_atomic_load(p, __ATOMIC_RELAXED, __HIP_MEMORY_SCOPE_AGENT);
      u.q[1] = __hip_atomic_load(p + 1, __ATOMIC_RELAXED, __HIP_MEMORY_SCOPE_AGENT);
      int q = r * 64 + (kg & 56) + ((kg & 7) ^ (r & 7));
      *(bf16x8*)&Hs[q * 8] = u.v;
    }
    __syncthreads();
    bf16x8 af[16];
#pragma unroll
    for (int ks = 0; ks < 16; ks++) {
      int g2 = ks * 4 + quad;
      int q = ar * 64 + (g2 & 56) + ((g2 & 7) ^ (ar & 7));
      af[ks] = *(const bf16x8*)&Hs[q * 8];
    }
    f32x4 acc[3] = {};
#pragma unroll
    for (int ks = 0; ks < 16; ks++)
#pragma unroll
      for (int g = 0; g < 3; g++)
        acc[g] = __builtin_amdgcn_mfma_f32_16x16x32_bf16(af[ks], wf[g][ks], acc[g], 0, 0, 0);

    const int s_orig = dir ? (S_ - 1 - t) : t;
#pragma unroll
    for (int rg = 0; rg < 4; rg++) {
      int b = brow0 + rg;
      float r = sigf(xgv[rg][0] + acc[0][rg] + br);
      float z = sigf(xgv[rg][1] + acc[1][rg] + bz);
      float n = tanhf(xgv[rg][2] + r * (acc[2][rg] + bn));
      float h = (1.f - z) * n + z * hreg[rg];
      hreg[rg] = h;
      __hip_bfloat16 hb = __float2bfloat16(h);
      unsigned short us;
      __builtin_memcpy(&us, &hb, 2);
      __hip_atomic_store((unsigned short*)(hn + (size_t)(dir * B_ + b) * H_ + j), us,
                         __ATOMIC_RELAXED, __HIP_MEMORY_SCOPE_AGENT);
      rnn[((size_t)b * S_ + s_orig) * (2 * H_) + dir * H_ + j] = hb;
    }

    if (t + 1 < S_) {
      float xgn[4][3];
#pragma unroll
      for (int rg = 0; rg < 4; rg++) {
        const __hip_bfloat16* xr = xg + ((size_t)(t + 1) * B_ + brow0 + rg) * G3_;
        xgn[rg][0] = __bfloat162float(xr[j]);
        xgn[rg][1] = __bfloat162float(xr[H_ + j]);
        xgn[rg][2] = __bfloat162float(xr[2 * H_ + j]);
      }
      __syncthreads();
      if (tid == 0)
        __hip_atomic_store(my_flag, (unsigned)(t + 1), __ATOMIC_RELAXED,
                           __HIP_MEMORY_SCOPE_AGENT);
      if (w == 0) {
        unsigned int* fl = arrive + (size_t)(gi * 16 + (lane & 15)) * 64;
        for (int spin = 0; spin < (1 << 17); spin++) {
          unsigned v = (lane < 16)
                           ? __hip_atomic_load(fl, __ATOMIC_RELAXED, __HIP_MEMORY_SCOPE_AGENT)
                           : (unsigned)(t + 1);
          if (__ballot(v >= (unsigned)(t + 1)) == ~0ull) break;
          __builtin_amdgcn_s_sleep(1);
        }
      }
      __syncthreads();
#pragma unroll
      for (int rg = 0; rg < 4; rg++) {
        xgv[rg][0] = xgn[rg][0]; xgv[rg][1] = xgn[rg][1]; xgv[rg][2] = xgn[rg][2];
      }
    }
  }
}

// ---------------------------------------------------------------------------
// fp32 tiled GEMM (small doc GEMMs)
// ---------------------------------------------------------------------------
template <int ACT>
__global__ __launch_bounds__(256) void gemm_nt(const float* __restrict__ A,
                                               const float* __restrict__ W,
                                               const float* __restrict__ bias,
                                               float* __restrict__ C, int N, int K) {
  __shared__ float As[16][68];
  __shared__ float Bs[16][68];
  const int t = threadIdx.x;
  const int tx = t & 15, ty = t >> 4;
  const int m0 = blockIdx.y * 64, n0 = blockIdx.x * 64;
  const int lr = t >> 2, lc = t & 3;
  const float* Arow = A + (size_t)(m0 + lr) * K;
  const float* Wrow = W + (size_t)(n0 + lr) * K;
  float acc[4][4] = {};
  for (int kc = 0; kc < K; kc += 16) {
    float4 av = *(const float4*)(Arow + kc + lc * 4);
    float4 wv = *(const float4*)(Wrow + kc + lc * 4);
    As[lc * 4 + 0][lr] = av.x; As[lc * 4 + 1][lr] = av.y;
    As[lc * 4 + 2][lr] = av.z; As[lc * 4 + 3][lr] = av.w;
    Bs[lc * 4 + 0][lr] = wv.x; Bs[lc * 4 + 1][lr] = wv.y;
    Bs[lc * 4 + 2][lr] = wv.z; Bs[lc * 4 + 3][lr] = wv.w;
    __syncthreads();
#pragma unroll
    for (int k = 0; k < 16; k++) {
      float4 a4 = *(const float4*)&As[k][ty * 4];
      float4 b4 = *(const float4*)&Bs[k][tx * 4];
      float ar[4] = {a4.x, a4.y, a4.z, a4.w};
      float br[4] = {b4.x, b4.y, b4.z, b4.w};
#pragma unroll
      for (int i = 0; i < 4; i++)
#pragma unroll
        for (int jx = 0; jx < 4; jx++) acc[i][jx] = fmaf(ar[i], br[jx], acc[i][jx]);
    }
    __syncthreads();
  }
  float4 bv = *(const float4*)&bias[n0 + tx * 4];
  float bb[4] = {bv.x, bv.y, bv.z, bv.w};
#pragma unroll
  for (int i = 0; i < 4; i++) {
    float o[4];
#pragma unroll
    for (int jx = 0; jx < 4; jx++) {
      float v = acc[i][jx] + bb[jx];
      if (ACT == 1) v = fmaxf(v, 0.f);
      if (ACT == 2) v = tanhf(v);
      o[jx] = v;
    }
    *(float4*)&C[(size_t)(m0 + ty * 4 + i) * N + n0 + tx * 4] = float4{o[0], o[1], o[2], o[3]};
  }
}

// ------------------------- fused prep kernel -------------------------------
#define PREP_XC    12800
#define PREP_CAST1 (PREP_XC + 1536)
#define PREP_CAST2 (PREP_CAST1 + 1536)
#define PREP_CAST3 (PREP_CAST2 + 512)
#define PREP_PACK1 (PREP_CAST3 + 768)
#define PREP_PACK2 (PREP_PACK1 + 768)
#define PREP_TSIM  (PREP_PACK2 + 256)
#define PREP_ZH    (PREP_TSIM + 128)
#define PREP_ZF    (PREP_ZH + 16)
#define PREP_POS   (PREP_ZF)
__global__ __launch_bounds__(256) void prep_all(
    const float* __restrict__ x, const float* __restrict__ Wihf,
    const float* __restrict__ Wihb, const float* __restrict__ Wsent,
    const float* __restrict__ Whhf, const float* __restrict__ Whhb,
    const float* __restrict__ Wsim,
    const float* __restrict__ pos_emb, const float* __restrict__ pos_lin,
    const float* __restrict__ seg_emb, const float* __restrict__ seg_lin,
    __hip_bfloat16* __restrict__ x_bf,
    __hip_bfloat16* __restrict__ Wihf_b, __hip_bfloat16* __restrict__ Wihb_b,
    __hip_bfloat16* __restrict__ Wsent_b, __hip_bfloat16* __restrict__ Wpf,
    __hip_bfloat16* __restrict__ Wpb, __hip_bfloat16* __restrict__ WsimT_b,
    __hip_bfloat16* __restrict__ h16a, unsigned int* __restrict__ arrive,
    float* __restrict__ pos_logits, float* __restrict__ seg_vals) {
  const int blk = blockIdx.x, tid = threadIdx.x;
  if (blk < PREP_XC) {
    int i = blk * 1024 + tid * 4;
    float4 v = *(const float4*)(x + i);
    x_bf[i] = __float2bfloat16(v.x); x_bf[i + 1] = __float2bfloat16(v.y);
    x_bf[i + 2] = __float2bfloat16(v.z); x_bf[i + 3] = __float2bfloat16(v.w);
  } else if (blk < PREP_CAST2) {
    const float* src = (blk < PREP_CAST1) ? Wihf : Wihb;
    __hip_bfloat16* dst = (blk < PREP_CAST1) ? Wihf_b : Wihb_b;
    int lb = (blk < PREP_CAST1) ? blk - PREP_XC : blk - PREP_CAST1;
    int i = lb * 1024 + tid * 4;
    float4 v = *(const float4*)(src + i);
    dst[i] = __float2bfloat16(v.x); dst[i + 1] = __float2bfloat16(v.y);
    dst[i + 2] = __float2bfloat16(v.z); dst[i + 3] = __float2bfloat16(v.w);
  } else if (blk < PREP_CAST3) {
    int i = (blk - PREP_CAST2) * 1024 + tid * 4;
    float4 v = *(const float4*)(Wsent + i);
    Wsent_b[i] = __float2bfloat16(v.x); Wsent_b[i + 1] = __float2bfloat16(v.y);
    Wsent_b[i + 2] = __float2bfloat16(v.z); Wsent_b[i + 3] = __float2bfloat16(v.w);
  } else if (blk < PREP_PACK2) {
    const float* src = (blk < PREP_PACK1) ? Whhf : Whhb;
    __hip_bfloat16* dst = (blk < PREP_PACK1) ? Wpf : Wpb;
    int lb = (blk < PREP_PACK1) ? blk - PREP_CAST3 : blk - PREP_PACK1;
    int e = lb * 1024 + tid * 4;
    int row = e >> 9, k = e & 511;
    int g = row >> 9, j = row & 511;
    int p = (j >> 4) * 48 + g * 16 + (j & 15);
    float4 v = *(const float4*)(src + (size_t)row * 512 + k);
    __hip_bfloat16* d = dst + (size_t)p * 512 + k;
    d[0] = __float2bfloat16(v.x); d[1] = __float2bfloat16(v.y);
    d[2] = __float2bfloat16(v.z); d[3] = __float2bfloat16(v.w);
  } else if (blk < PREP_TSIM) {
    __shared__ float tile[32][33];
    int tb = blk - PREP_PACK2;
    int ti = tb >> 4, tj = tb & 15;
    int r = tid >> 3, c4 = (tid & 7) * 4;
    float4 v = *(const float4*)(Wsim + (size_t)(ti * 32 + r) * 512 + tj * 32 + c4);
    tile[r][c4] = v.x; tile[r][c4 + 1] = v.y; tile[r][c4 + 2] = v.z; tile[r][c4 + 3] = v.w;
    __syncthreads();
    __hip_bfloat16* d = WsimT_b + (size_t)(tj * 32 + r) * 512 + ti * 32 + c4;
    d[0] = __float2bfloat16(tile[c4][r]);
    d[1] = __float2bfloat16(tile[c4 + 1][r]);
    d[2] = __float2bfloat16(tile[c4 + 2][r]);
    d[3] = __float2bfloat16(tile[c4 + 3][r]);
  } else if (blk < PREP_ZH) {
    int i = (blk - PREP_TSIM) * 2048 + tid * 8;
    float4 z = {0.f, 0.f, 0.f, 0.f};
    *(float4*)((short*)h16a + i) = z;
  } else if (blk < PREP_ZF) {
    int i = (blk - PREP_ZH) * 1024 + tid * 4;
    float4 z = {0.f, 0.f, 0.f, 0.f};
    *(float4*)(arrive + i) = z;
  } else {
    if (tid < S_) {
      int idx = tid + 1; if (idx > 25) idx = 25;
      float a = 0.f;
      for (int k = 0; k < 50; k++) a += pos_emb[idx * 50 + k] * pos_lin[k];
      pos_logits[tid] = a;
    }
    if (tid < 5) {
      float a = 0.f;
      for (int k = 0; k < 50; k++) a += seg_emb[tid * 50 + k] * seg_lin[k];
      seg_vals[tid] = a;
    }
  }
}

__global__ __launch_bounds__(256) void avg_kernel(const __hip_bfloat16* __restrict__ sent,
                                                  const int* __restrict__ ns,
                                                  float* __restrict__ avg) {
  int b = blockIdx.x, tid = threadIdx.x;
  const __hip_bfloat16* base = sent + (size_t)b * S_ * SENT_;
  float a0 = 0.f, a1 = 0.f;
  for (int s = 0; s < S_; s++) {
    a0 += __bfloat162float(base[s * SENT_ + tid]);
    a1 += __bfloat162float(base[s * SENT_ + 256 + tid]);
  }
  float inv = 1.0f / (float)ns[b];
  avg[(size_t)b * SENT_ + tid] = a0 * inv;
  avg[(size_t)b * SENT_ + 256 + tid] = a1 * inv;
}

// One 64-lane wave per batch. Fuses the former static_kernel: content
// (sent·wcont) and salience (sent·doc) ride the same shfl reduction as the
// novelty dot — sent(b,t) is loaded anyway. Zero LDS, zero barriers.
__global__ __launch_bounds__(64) void novelty_wave(
    const __hip_bfloat16* __restrict__ sent, const __hip_bfloat16* __restrict__ U,
    const float* __restrict__ doc, const float* __restrict__ wcont,
    const float* __restrict__ bcont, const int* __restrict__ ns,
    const float* __restrict__ pos_logits, const float* __restrict__ seg_vals,
    const float* __restrict__ bias, float* __restrict__ out) {
  int b = blockIdx.x, lane = threadIdx.x;
  float s[8] = {0.f, 0.f, 0.f, 0.f, 0.f, 0.f, 0.f, 0.f};
  float wc[8], dc[8];
#pragma unroll
  for (int k = 0; k < 8; k++) {
    wc[k] = wcont[lane * 8 + k];
    dc[k] = doc[(size_t)b * SENT_ + lane * 8 + k];
  }
  const float cb = bcont[0] + bias[0];
  const float chunk = rintf((float)ns[b] * 0.25f);
  for (int t = 0; t < S_; t++) {
    bf16x8 uv = *(const bf16x8*)(U + ((size_t)b * S_ + t) * SENT_ + lane * 8);
    bf16x8 sv = *(const bf16x8*)(sent + ((size_t)b * S_ + t) * SENT_ + lane * 8);
    float pU = 0.f, pS = 0.f;
#pragma unroll
    for (int k = 0; k < 8; k++) {
      float svf = b2f(sv[k]);
      pU += b2f(uv[k]) * tanhf(s[k]);
      pS += svf * (wc[k] + dc[k]);
    }
#pragma unroll
    for (int off = 32; off; off >>= 1) {
      pU += __shfl_down(pU, off);
      pS += __shfl_down(pS, off);
    }
    float sim = __shfl(pU, 0);
    float stat = __shfl(pS, 0);
    float relf = fminf(fmaxf(ceilf((float)(t + 1) / chunk), 0.f), 4.f);
    float logit = stat + cb + pos_logits[t] + seg_vals[(int)relf] - sim;
    if (lane == 0) out[(size_t)t * B_ + b] = logit;
    float sg = sigf(logit);
#pragma unroll
    for (int k = 0; k < 8; k++) s[k] += b2f(sv[k]) * sg;
  }
}

extern "C" void kernel_launch(void* const* d_in, const int* in_sizes, int n_in,
                              void* d_out, int out_size, void* d_ws, size_t ws_size,
                              hipStream_t stream) {
  const float* x = (const float*)d_in[0];
  const int* ns = (const int*)d_in[1];
  const float* Wihf = (const float*)d_in[2];
  const float* Whhf = (const float*)d_in[3];
  const float* bihf = (const float*)d_in[4];
  const float* bhhf = (const float*)d_in[5];
  const float* Wihb = (const float*)d_in[6];
  const float* Whhb = (const float*)d_in[7];
  const float* bihb = (const float*)d_in[8];
  const float* bhhb = (const float*)d_in[9];
  const float* Wsent = (const float*)d_in[10];
  const float* bsent = (const float*)d_in[11];
  const float* wcont = (const float*)d_in[12];
  const float* bcont = (const float*)d_in[13];
  const float* Wd1 = (const float*)d_in[14];
  const float* bd1 = (const float*)d_in[15];
  const float* Wd2 = (const float*)d_in[16];
  const float* bd2 = (const float*)d_in[17];
  const float* Wsim = (const float*)d_in[18];
  const float* bias = (const float*)d_in[19];
  const float* pos_emb = (const float*)d_in[20];
  const float* pos_lin = (const float*)d_in[21];
  const float* seg_emb = (const float*)d_in[22];
  const float* seg_lin = (const float*)d_in[23];
  float* out = (float*)d_out;

  char* base = (char*)d_ws;
  size_t off = 0;
  auto alloc = [&](size_t bytes) { char* p = base + off; off += (bytes + 255) & ~255ull; return p; };
  __hip_bfloat16* xgf_b  = (__hip_bfloat16*)alloc((size_t)S_ * B_ * G3_ * 2);
  __hip_bfloat16* xgb_b  = (__hip_bfloat16*)alloc((size_t)S_ * B_ * G3_ * 2);
  char* region1          = alloc((size_t)B_ * S_ * I_ * 2);  // x_bf, later sent_b+U_b
  __hip_bfloat16* x_bf   = (__hip_bfloat16*)region1;
  __hip_bfloat16* sent_b = (__hip_bfloat16*)region1;
  __hip_bfloat16* U_b    = (__hip_bfloat16*)(region1 + (size_t)B_ * S_ * SENT_ * 2);
  __hip_bfloat16* rnn_b  = (__hip_bfloat16*)alloc((size_t)B_ * S_ * 2 * H_ * 2);
  __hip_bfloat16* Wihf_b = (__hip_bfloat16*)alloc((size_t)G3_ * I_ * 2);
  __hip_bfloat16* Wihb_b = (__hip_bfloat16*)alloc((size_t)G3_ * I_ * 2);
  __hip_bfloat16* Wpf    = (__hip_bfloat16*)alloc((size_t)G3_ * H_ * 2);
  __hip_bfloat16* Wpb    = (__hip_bfloat16*)alloc((size_t)G3_ * H_ * 2);
  __hip_bfloat16* Wsent_b= (__hip_bfloat16*)alloc((size_t)SENT_ * 2 * H_ * 2);
  __hip_bfloat16* WsimT_b= (__hip_bfloat16*)alloc((size_t)SENT_ * SENT_ * 2);
  __hip_bfloat16* h16a   = (__hip_bfloat16*)alloc(2 * (size_t)B_ * H_ * 2);
  __hip_bfloat16* h16b   = (__hip_bfloat16*)alloc(2 * (size_t)B_ * H_ * 2);
  unsigned int* arrive   = (unsigned int*)alloc(256 * 64 * 4);
  float* avg             = (float*)alloc((size_t)B_ * SENT_ * 4);
  float* d1buf           = (float*)alloc((size_t)B_ * DOC_ * 4);
  float* doc             = (float*)alloc((size_t)B_ * SENT_ * 4);
  float* poslog          = (float*)alloc(256);
  float* segvals         = (float*)alloc(64);
  (void)ws_size;

  prep_all<<<PREP_POS + 1, 256, 0, stream>>>(
      x, Wihf, Wihb, Wsent, Whhf, Whhb, Wsim, pos_emb, pos_lin, seg_emb, seg_lin,
      x_bf, Wihf_b, Wihb_b, Wsent_b, Wpf, Wpb, WsimT_b, h16a, arrive, poslog, segvals);

  mfma_xg<<<dim3(G3_ / 128, (S_ * B_) / 128, 2), 256, 0, stream>>>(x_bf, Wihf_b, bihf, Wihb_b, bihb, xgf_b, xgb_b);

  gru_persistent<<<dim3(256), dim3(256), 0, stream>>>(
      xgf_b, xgb_b, Wpf, Wpb, bhhf, bhhb, h16a, h16b, rnn_b, arrive);

  mfma_nt<1, true><<<dim3(SENT_ / 128, (B_ * S_) / 128), 256, 0, stream>>>(rnn_b, Wsent_b, bsent, sent_b, SENT_, 2 * H_);
  avg_kernel<<<B_, 256, 0, stream>>>(sent_b, ns, avg);
  gemm_nt<2><<<dim3(DOC_ / 64, B_ / 64), 256, 0, stream>>>(avg, Wd1, bd1, d1buf, DOC_, SENT_);
  gemm_nt<0><<<dim3(SENT_ / 64, B_ / 64), 256, 0, stream>>>(d1buf, Wd2, bd2, doc, SENT_, DOC_);

  mfma_nt<0, false><<<dim3(SENT_ / 128, (B_ * S_) / 128), 256, 0, stream>>>(sent_b, WsimT_b, nullptr, U_b, SENT_, SENT_);

  novelty_wave<<<B_, 64, 0, stream>>>(sent_b, U_b, doc, wcont, bcont, ns, poslog, segvals, bias, out);
}